// Round 11
// baseline (166.588 us; speedup 1.0000x reference)
//
#include <hip/hip_runtime.h>

// CensoredLoss:
//   d_in[0] = outputs [B, T=512, 4] f32
//   d_in[1] = targets [B, T=512, 5] f32
// out: scalar f32 = -sum(loss1+loss2) / count   (mask redundant for the loss)
// count = sum_b (tmax_b + 1).
//
// One row per WAVE, single fused kernel (last-block finalize).
// Per row: 2-round probe (byte-optimal) -> exact tmax; bulk targets+outputs
// loads predicated on the prefix; loss blocks guarded wave-uniformly;
// 4<->5 regroup through wave-private LDS with the proven fence pair
// (""/lgkmcnt(0)); zero hot-path __syncthreads.
// Finalize: per-block partials -> device-scope completion counter -> last
// block reduces all partials in f64 and writes the scalar.

#define EPSF 1e-8f
#define T_DIM 512
#define LN2F 0.69314718055994530942f

__device__ __forceinline__ float row_loss(
    const float4* __restrict__ outs4, const float4* __restrict__ tgts4,
    int row, int tmax, float* my, float4* myv, int lane, float acc)
{
    const int K = tmax >> 6;
    const int flim = 5 * tmax + 4;
    const float4* tb = tgts4 + (size_t)row * 640;
    const float4* op = outs4 + (size_t)row * T_DIM;

    float4 T[10];
    #pragma unroll
    for (int k = 0; k < 10; ++k) {
        T[k] = float4{0.f, 0.f, 0.f, 0.f};
        if (256 * k + 4 * lane <= flim) T[k] = tb[64 * k + lane];
    }
    float4 O[8];
    #pragma unroll
    for (int m = 0; m < 8; ++m) {
        O[m] = float4{0.f, 0.f, 0.f, 0.f};
        if (64 * m + lane <= tmax) O[m] = op[64 * m + lane];
    }

    // chunk 0: t in [0,256)
    asm volatile("" ::: "memory");                       // WAR
    #pragma unroll
    for (int k = 0; k < 5; ++k)
        myv[64 * k + lane] = T[k];
    asm volatile("s_waitcnt lgkmcnt(0)" ::: "memory");   // RAW
    #pragma unroll
    for (int q = 0; q < 4; ++q) {
        if (64 * q <= tmax) {                            // wave-uniform
            const float4 o = O[q];
            const float cens = 1.0f - (o.x + o.y + o.z + o.w);
            const float* p = my + 5 * (64 * q + lane);
            acc += p[0] * __log2f(cens + EPSF)
                 + p[1] * __log2f(o.x + EPSF)
                 + p[2] * __log2f(o.y + EPSF)
                 + p[3] * __log2f(o.z + EPSF)
                 + p[4] * __log2f(o.w + EPSF);
        }
    }

    // chunk 1: t in [256,512)
    if (K >= 4) {                                        // wave-uniform
        asm volatile("" ::: "memory");
        #pragma unroll
        for (int k = 0; k < 5; ++k)
            myv[64 * k + lane] = T[5 + k];
        asm volatile("s_waitcnt lgkmcnt(0)" ::: "memory");
        #pragma unroll
        for (int q = 4; q < 8; ++q) {
            if (64 * q <= tmax) {
                const float4 o = O[q];
                const float cens = 1.0f - (o.x + o.y + o.z + o.w);
                const float* p = my + 5 * (64 * (q - 4) + lane);
                acc += p[0] * __log2f(cens + EPSF)
                     + p[1] * __log2f(o.x + EPSF)
                     + p[2] * __log2f(o.y + EPSF)
                     + p[3] * __log2f(o.z + EPSF)
                     + p[4] * __log2f(o.w + EPSF);
            }
        }
    }
    return acc;
}

__global__ __launch_bounds__(256) void censored_loss_fused(
    const float4* __restrict__ outs4,   // [B*512]
    const float4* __restrict__ tgts4,   // [B*640]
    float* __restrict__ part_loss,      // [nblk]
    int* __restrict__ part_cnt,         // [nblk]
    unsigned int* __restrict__ done_ctr,
    float* __restrict__ out,
    int B, int nblk)
{
    __shared__ float tg[4][1280];
    __shared__ float bl_loss;
    __shared__ int bl_cnt;
    __shared__ int is_last;

    const int tid = threadIdx.x;
    const int wave = tid >> 6, lane = tid & 63;
    const int row = blockIdx.x * 4 + wave;    // one row per wave
    float* my = tg[wave];
    float4* myv = (float4*)my;
    const float* tgf = (const float*)tgts4;

    if (tid == 0) { bl_loss = 0.f; bl_cnt = 0; }
    __syncthreads();

    float acc = 0.f;
    int cnt = 0;

    if (row < B) {
        const size_t fbase = (size_t)row * 2560;

        // probe round 1: t = 64k, lanes 0-7
        float p1 = 0.f;
        if (lane < 8) p1 = tgf[fbase + 320 * lane];
        const unsigned long long m1 = __ballot(p1 != 0.f);
        const int K = 63 - __clzll(m1 | 1ull);

        // probe round 2: t = 64K + lane (contiguous 1280B, within prefix)
        const float p2 = tgf[fbase + 320 * K + 5 * lane];
        const unsigned long long m2 = __ballot(p2 != 0.f);
        const int tmax = 64 * K + (63 - __clzll(m2 | 1ull));

        cnt = tmax + 1;
        acc = row_loss(outs4, tgts4, row, tmax, my, myv, lane, acc);
    }

    #pragma unroll
    for (int off = 1; off < 64; off <<= 1)
        acc += __shfl_xor(acc, off);
    if (lane == 0) {
        atomicAdd(&bl_loss, acc * LN2F);
        atomicAdd(&bl_cnt, cnt);
    }
    __syncthreads();

    if (tid == 0) {
        part_loss[blockIdx.x] = bl_loss;
        part_cnt[blockIdx.x] = bl_cnt;
        __threadfence();                               // release partials
        const unsigned prev = atomicAdd(done_ctr, 1u);
        is_last = (prev == (unsigned)(nblk - 1)) ? 1 : 0;
    }
    __syncthreads();

    if (is_last) {
        __threadfence();                               // acquire partials
        double ls = 0.0;
        long long cs = 0;
        for (int i = tid; i < nblk; i += 256) {
            ls += (double)part_loss[i];
            cs += (long long)part_cnt[i];
        }
        #pragma unroll
        for (int off = 1; off < 64; off <<= 1) {
            ls += __shfl_xor(ls, off);
            cs += __shfl_xor(cs, off);
        }
        __shared__ double lw[4];
        __shared__ long long cw[4];
        if (lane == 0) { lw[wave] = ls; cw[wave] = cs; }
        __syncthreads();
        if (tid == 0) {
            const double L = lw[0] + lw[1] + lw[2] + lw[3];
            const long long C = cw[0] + cw[1] + cw[2] + cw[3];
            out[0] = (C > 0) ? (float)(-L / (double)C) : 0.0f;
        }
    }
}

extern "C" void kernel_launch(void* const* d_in, const int* in_sizes, int n_in,
                              void* d_out, int out_size, void* d_ws, size_t ws_size,
                              hipStream_t stream) {
    const float4* outs4 = (const float4*)d_in[0];
    const float4* tgts4 = (const float4*)d_in[1];
    float* out = (float*)d_out;

    const int B = in_sizes[1] / (T_DIM * 5);
    const int nblk = (B + 3) / 4;                      // one row per wave

    float* part_loss = (float*)d_ws;
    int* part_cnt = (int*)((char*)d_ws + (size_t)nblk * sizeof(float));
    unsigned int* done_ctr =
        (unsigned int*)((char*)d_ws + (size_t)nblk * (sizeof(float) + sizeof(int)));

    hipMemsetAsync(done_ctr, 0, sizeof(unsigned int), stream);
    censored_loss_fused<<<nblk, 256, 0, stream>>>(outs4, tgts4, part_loss,
                                                  part_cnt, done_ctr, out, B, nblk);
}

// Round 12
// 94.012 us; speedup vs baseline: 1.7720x; 1.7720x over previous
//
#include <hip/hip_runtime.h>

// CensoredLoss:
//   d_in[0] = outputs [B, T=512, 4] f32
//   d_in[1] = targets [B, T=512, 5] f32
// out: scalar f32 = -sum(loss1+loss2) / count   (mask redundant for the loss)
// count = sum_b (tmax_b + 1).
//
// R10's proven hot path (2 rows/wave, fused 2-round probes, prefix-predicated
// loads, guarded loss blocks, wave-private LDS regroup with ""/lgkmcnt(0)
// fence pair) + FENCE-FREE fused finalize:
//   - block partials -> global atomicAdd (coherent at the fabric point,
//     no cache maintenance; NO __threadfence -> no per-block L2 writeback,
//     which is what destroyed R11: 4096 wbl2-class flushes = 260us).
//   - __syncthreads() after the adds: compiler drains vmcnt(0) before
//     s_barrier, so every wave's adds are complete before tid0 increments
//     the completion counter.
//   - last block (prev == nblk-1) reads totals via atomicAdd(p, 0) RMWs
//     (coherence-point reads, no stale L1) and writes the scalar.

#define EPSF 1e-8f
#define T_DIM 512
#define LN2F 0.69314718055994530942f

__device__ __forceinline__ float row_loss(
    const float4* __restrict__ outs4, const float4* __restrict__ tgts4,
    int row, int tmax, float* my, float4* myv, int lane, float acc)
{
    const int K = tmax >> 6;
    const int flim = 5 * tmax + 4;
    const float4* tb = tgts4 + (size_t)row * 640;
    const float4* op = outs4 + (size_t)row * T_DIM;

    float4 T[10];
    #pragma unroll
    for (int k = 0; k < 10; ++k) {
        T[k] = float4{0.f, 0.f, 0.f, 0.f};
        if (256 * k + 4 * lane <= flim) T[k] = tb[64 * k + lane];
    }
    float4 O[8];
    #pragma unroll
    for (int m = 0; m < 8; ++m) {
        O[m] = float4{0.f, 0.f, 0.f, 0.f};
        if (64 * m + lane <= tmax) O[m] = op[64 * m + lane];
    }

    // chunk 0: t in [0,256)
    asm volatile("" ::: "memory");                       // WAR
    #pragma unroll
    for (int k = 0; k < 5; ++k)
        myv[64 * k + lane] = T[k];
    asm volatile("s_waitcnt lgkmcnt(0)" ::: "memory");   // RAW
    #pragma unroll
    for (int q = 0; q < 4; ++q) {
        if (64 * q <= tmax) {                            // wave-uniform
            const float4 o = O[q];
            const float cens = 1.0f - (o.x + o.y + o.z + o.w);
            const float* p = my + 5 * (64 * q + lane);
            acc += p[0] * __log2f(cens + EPSF)
                 + p[1] * __log2f(o.x + EPSF)
                 + p[2] * __log2f(o.y + EPSF)
                 + p[3] * __log2f(o.z + EPSF)
                 + p[4] * __log2f(o.w + EPSF);
        }
    }

    // chunk 1: t in [256,512)
    if (K >= 4) {                                        // wave-uniform
        asm volatile("" ::: "memory");
        #pragma unroll
        for (int k = 0; k < 5; ++k)
            myv[64 * k + lane] = T[5 + k];
        asm volatile("s_waitcnt lgkmcnt(0)" ::: "memory");
        #pragma unroll
        for (int q = 4; q < 8; ++q) {
            if (64 * q <= tmax) {
                const float4 o = O[q];
                const float cens = 1.0f - (o.x + o.y + o.z + o.w);
                const float* p = my + 5 * (64 * (q - 4) + lane);
                acc += p[0] * __log2f(cens + EPSF)
                     + p[1] * __log2f(o.x + EPSF)
                     + p[2] * __log2f(o.y + EPSF)
                     + p[3] * __log2f(o.z + EPSF)
                     + p[4] * __log2f(o.w + EPSF);
            }
        }
    }
    return acc;
}

__global__ __launch_bounds__(256) void censored_loss_fused(
    const float4* __restrict__ outs4,   // [B*512]
    const float4* __restrict__ tgts4,   // [B*640]
    float* __restrict__ gloss,          // [1] global f32 accumulator
    int* __restrict__ gcnt,             // [1]
    unsigned int* __restrict__ done_ctr,// [1]
    float* __restrict__ out,
    int B, int NW, int nblk)
{
    __shared__ float tg[4][1280];
    __shared__ float bl_loss;
    __shared__ int bl_cnt;

    const int tid = threadIdx.x;
    const int wave = tid >> 6, lane = tid & 63;
    const int gwave = blockIdx.x * 4 + wave;
    float* my = tg[wave];
    float4* myv = (float4*)my;
    const float* tgf = (const float*)tgts4;

    if (tid == 0) { bl_loss = 0.f; bl_cnt = 0; }
    __syncthreads();

    float acc = 0.f;
    int cnt = 0;

    for (int r0 = gwave; r0 < B; r0 += 2 * NW) {
        const int r1 = r0 + NW;
        const bool have1 = r1 < B;

        // ---- fused probe round 1 (both rows, one load in flight) ----
        float p1 = 0.f;
        if (lane < 8) p1 = tgf[(size_t)r0 * 2560 + 320 * lane];
        else if (lane < 16 && have1) p1 = tgf[(size_t)r1 * 2560 + 320 * (lane - 8)];
        const unsigned long long m1 = __ballot(p1 != 0.f);
        const int K0 = 63 - __clzll((m1 & 0xFFull) | 1ull);
        const int K1 = 63 - __clzll(((m1 >> 8) & 0xFFull) | 1ull);

        // ---- fused probe round 2 (two independent loads in flight) ----
        const float p2a = tgf[(size_t)r0 * 2560 + 320 * K0 + 5 * lane];
        float p2b = 0.f;
        if (have1) p2b = tgf[(size_t)r1 * 2560 + 320 * K1 + 5 * lane];
        const unsigned long long m2a = __ballot(p2a != 0.f);
        const unsigned long long m2b = __ballot(p2b != 0.f);
        const int tmax0 = 64 * K0 + (63 - __clzll(m2a | 1ull));
        const int tmax1 = 64 * K1 + (63 - __clzll(m2b | 1ull));

        cnt += tmax0 + 1;
        acc = row_loss(outs4, tgts4, r0, tmax0, my, myv, lane, acc);
        if (have1) {
            cnt += tmax1 + 1;
            acc = row_loss(outs4, tgts4, r1, tmax1, my, myv, lane, acc);
        }
    }

    #pragma unroll
    for (int off = 1; off < 64; off <<= 1)
        acc += __shfl_xor(acc, off);
    if (lane == 0) {
        atomicAdd(&bl_loss, acc * LN2F);
        atomicAdd(&bl_cnt, cnt);
    }
    __syncthreads();

    // one global atomic pair per block (coherence-point RMW, no fences)
    if (tid == 0) {
        atomicAdd(gloss, bl_loss);
        atomicAdd(gcnt, bl_cnt);
    }
    __syncthreads();   // barrier drains vmcnt(0): adds are complete past here

    if (tid == 0) {
        const unsigned prev = atomicAdd(done_ctr, 1u);
        if (prev == (unsigned)(nblk - 1)) {
            // all blocks' adds completed (each preceded its ctr-inc by a
            // vmcnt-draining barrier); RMW-read the totals coherently.
            const float L = atomicAdd(gloss, 0.0f);
            const int C = atomicAdd(gcnt, 0);
            out[0] = (C > 0) ? (-L / (float)C) : 0.0f;
        }
    }
}

extern "C" void kernel_launch(void* const* d_in, const int* in_sizes, int n_in,
                              void* d_out, int out_size, void* d_ws, size_t ws_size,
                              hipStream_t stream) {
    const float4* outs4 = (const float4*)d_in[0];
    const float4* tgts4 = (const float4*)d_in[1];
    float* out = (float*)d_out;

    const int B = in_sizes[1] / (T_DIM * 5);

    int nblk = (B + 7) / 8;              // 2 rows per wave
    if (nblk > 2048) nblk = 2048;
    if (nblk < 1) nblk = 1;
    const int NW = nblk * 4;

    float* gloss = (float*)d_ws;
    int* gcnt = (int*)((char*)d_ws + sizeof(float));
    unsigned int* done_ctr = (unsigned int*)((char*)d_ws + 2 * sizeof(float));

    hipMemsetAsync(d_ws, 0, 3 * sizeof(float), stream);
    censored_loss_fused<<<nblk, 256, 0, stream>>>(outs4, tgts4, gloss, gcnt,
                                                  done_ctr, out, B, NW, nblk);
}

// Round 13
// 36.050 us; speedup vs baseline: 4.6210x; 2.6078x over previous
//
#include <hip/hip_runtime.h>

// CensoredLoss:
//   d_in[0] = outputs [B, T=512, 4] f32
//   d_in[1] = targets [B, T=512, 5] f32
// out: scalar f32 = -sum(loss1+loss2) / count   (mask redundant for the loss)
// count = sum_b (tmax_b + 1).
//
// R10 structure (proven 36.2 us) — reverted after R11/R12 fused-finalize
// regressions (same-cache-line device atomics serialize at the coherence
// point; per-block __threadfence additionally forces L2 writebacks on
// non-coherent XCD L2s). Two-kernel form: non-atomic per-block partials to
// distinct addresses + tiny finalize launch.
//
// Prefix property (data = uniform * prefix mask): tmax found by 2 probe
// rounds; each wave owns rows (w, w+NW) and fuses BOTH rows' probes into the
// same two rounds. Bulk loads predicated on the prefix; loss blocks guarded
// wave-uniformly; 4<->5 regroup through wave-private LDS with the proven
// fence pair (""/lgkmcnt(0)); zero hot-loop __syncthreads.

#define EPSF 1e-8f
#define T_DIM 512
#define LN2F 0.69314718055994530942f

__device__ __forceinline__ float row_loss(
    const float4* __restrict__ outs4, const float4* __restrict__ tgts4,
    int row, int tmax, float* my, float4* myv, int lane, float acc)
{
    const int K = tmax >> 6;                    // 0..7 valid 64-blocks - 1
    const int flim = 5 * tmax + 4;              // last needed flat float
    const float4* tb = tgts4 + (size_t)row * 640;
    const float4* op = outs4 + (size_t)row * T_DIM;

    float4 T[10];
    #pragma unroll
    for (int k = 0; k < 10; ++k) {
        T[k] = float4{0.f, 0.f, 0.f, 0.f};
        if (256 * k + 4 * lane <= flim) T[k] = tb[64 * k + lane];
    }
    float4 O[8];
    #pragma unroll
    for (int m = 0; m < 8; ++m) {
        O[m] = float4{0.f, 0.f, 0.f, 0.f};
        if (64 * m + lane <= tmax) O[m] = op[64 * m + lane];
    }

    // chunk 0: t in [0,256)
    asm volatile("" ::: "memory");                       // WAR
    #pragma unroll
    for (int k = 0; k < 5; ++k)
        myv[64 * k + lane] = T[k];
    asm volatile("s_waitcnt lgkmcnt(0)" ::: "memory");   // RAW
    #pragma unroll
    for (int q = 0; q < 4; ++q) {
        if (64 * q <= tmax) {                            // wave-uniform
            const float4 o = O[q];
            const float cens = 1.0f - (o.x + o.y + o.z + o.w);
            const float* p = my + 5 * (64 * q + lane);
            acc += p[0] * __log2f(cens + EPSF)
                 + p[1] * __log2f(o.x + EPSF)
                 + p[2] * __log2f(o.y + EPSF)
                 + p[3] * __log2f(o.z + EPSF)
                 + p[4] * __log2f(o.w + EPSF);
        }
    }

    // chunk 1: t in [256,512), only if any valid
    if (K >= 4) {                                        // wave-uniform
        asm volatile("" ::: "memory");
        #pragma unroll
        for (int k = 0; k < 5; ++k)
            myv[64 * k + lane] = T[5 + k];
        asm volatile("s_waitcnt lgkmcnt(0)" ::: "memory");
        #pragma unroll
        for (int q = 4; q < 8; ++q) {
            if (64 * q <= tmax) {
                const float4 o = O[q];
                const float cens = 1.0f - (o.x + o.y + o.z + o.w);
                const float* p = my + 5 * (64 * (q - 4) + lane);
                acc += p[0] * __log2f(cens + EPSF)
                     + p[1] * __log2f(o.x + EPSF)
                     + p[2] * __log2f(o.y + EPSF)
                     + p[3] * __log2f(o.z + EPSF)
                     + p[4] * __log2f(o.w + EPSF);
            }
        }
    }
    return acc;
}

__global__ __launch_bounds__(256) void censored_loss_rows(
    const float4* __restrict__ outs4,   // [B*512]
    const float4* __restrict__ tgts4,   // [B*640]
    float* __restrict__ part_loss,      // [nblk]
    int* __restrict__ part_cnt,         // [nblk]
    int B, int NW)
{
    __shared__ float tg[4][1280];
    __shared__ float bl_loss;
    __shared__ int bl_cnt;

    const int tid = threadIdx.x;
    const int wave = tid >> 6, lane = tid & 63;
    const int gwave = blockIdx.x * 4 + wave;
    float* my = tg[wave];
    float4* myv = (float4*)my;
    const float* tgf = (const float*)tgts4;

    if (tid == 0) { bl_loss = 0.f; bl_cnt = 0; }
    __syncthreads();

    float acc = 0.f;
    int cnt = 0;

    for (int r0 = gwave; r0 < B; r0 += 2 * NW) {
        const int r1 = r0 + NW;
        const bool have1 = r1 < B;

        // ---- fused probe round 1 (both rows, one load in flight) ----
        float p1 = 0.f;
        if (lane < 8) p1 = tgf[(size_t)r0 * 2560 + 320 * lane];
        else if (lane < 16 && have1) p1 = tgf[(size_t)r1 * 2560 + 320 * (lane - 8)];
        const unsigned long long m1 = __ballot(p1 != 0.f);
        const int K0 = 63 - __clzll((m1 & 0xFFull) | 1ull);
        const int K1 = 63 - __clzll(((m1 >> 8) & 0xFFull) | 1ull);

        // ---- fused probe round 2 (two independent loads in flight) ----
        const float p2a = tgf[(size_t)r0 * 2560 + 320 * K0 + 5 * lane];
        float p2b = 0.f;
        if (have1) p2b = tgf[(size_t)r1 * 2560 + 320 * K1 + 5 * lane];
        const unsigned long long m2a = __ballot(p2a != 0.f);
        const unsigned long long m2b = __ballot(p2b != 0.f);
        const int tmax0 = 64 * K0 + (63 - __clzll(m2a | 1ull));
        const int tmax1 = 64 * K1 + (63 - __clzll(m2b | 1ull));

        cnt += tmax0 + 1;
        acc = row_loss(outs4, tgts4, r0, tmax0, my, myv, lane, acc);
        if (have1) {
            cnt += tmax1 + 1;
            acc = row_loss(outs4, tgts4, r1, tmax1, my, myv, lane, acc);
        }
    }

    #pragma unroll
    for (int off = 1; off < 64; off <<= 1)
        acc += __shfl_xor(acc, off);
    if (lane == 0) {
        atomicAdd(&bl_loss, acc * LN2F);
        atomicAdd(&bl_cnt, cnt);
    }
    __syncthreads();
    if (tid == 0) {
        part_loss[blockIdx.x] = bl_loss;
        part_cnt[blockIdx.x] = bl_cnt;
    }
}

__global__ __launch_bounds__(256) void censored_loss_final(
    const float* __restrict__ part_loss,
    const int* __restrict__ part_cnt,
    int n, float* __restrict__ out)
{
    const int tid = threadIdx.x;
    double ls = 0.0;
    long long cs = 0;
    for (int i = tid; i < n; i += 256) {
        ls += (double)part_loss[i];
        cs += (long long)part_cnt[i];
    }
    #pragma unroll
    for (int off = 1; off < 64; off <<= 1) {
        ls += __shfl_xor(ls, off);
        cs += __shfl_xor(cs, off);
    }
    __shared__ double lw[4];
    __shared__ long long cw[4];
    const int wave = tid >> 6, lane = tid & 63;
    if (lane == 0) { lw[wave] = ls; cw[wave] = cs; }
    __syncthreads();
    if (tid == 0) {
        const double L = lw[0] + lw[1] + lw[2] + lw[3];
        const long long C = cw[0] + cw[1] + cw[2] + cw[3];
        out[0] = (C > 0) ? (float)(-L / (double)C) : 0.0f;
    }
}

extern "C" void kernel_launch(void* const* d_in, const int* in_sizes, int n_in,
                              void* d_out, int out_size, void* d_ws, size_t ws_size,
                              hipStream_t stream) {
    const float4* outs4 = (const float4*)d_in[0];
    const float4* tgts4 = (const float4*)d_in[1];
    float* out = (float*)d_out;

    const int B = in_sizes[1] / (T_DIM * 5);

    int nblk = (B + 7) / 8;              // 2 rows per wave
    if (nblk > 2048) nblk = 2048;
    if (nblk < 1) nblk = 1;
    const int NW = nblk * 4;

    float* part_loss = (float*)d_ws;
    int* part_cnt = (int*)((char*)d_ws + (size_t)nblk * sizeof(float));

    censored_loss_rows<<<nblk, 256, 0, stream>>>(outs4, tgts4, part_loss,
                                                 part_cnt, B, NW);
    censored_loss_final<<<1, 256, 0, stream>>>(part_loss, part_cnt, nblk, out);
}